// Round 15
// baseline (198.254 us; speedup 1.0000x reference)
//
#include <hip/hip_runtime.h>
#include <hip/hip_bf16.h>
#include <cstdint>
#include <cstddef>

using bf16 = __hip_bfloat16;
typedef __attribute__((ext_vector_type(8))) short bf16x8;  // 8 bf16 (4 VGPRs)
typedef __attribute__((ext_vector_type(4))) float f32x4;

static constexpr int B_ = 2, S_ = 1024, D_ = 512, H_ = 8;
static constexpr int M_ = B_ * S_;     // 2048 rows
static constexpr int CHUNKS_ = 32, CLEN_ = 32;  // S = CHUNKS * CLEN
static constexpr float EPS_ = 1e-6f;

__device__ __forceinline__ float sigmoidf_(float x) { return 1.0f / (1.0f + __expf(-x)); }

__device__ __forceinline__ short bf_hi(float v, float& rem) {
  bf16 h = __float2bfloat16(v);
  rem = v - __bfloat162float(h);
  return *(short*)&h;
}
__device__ __forceinline__ short bf_of(float v) {
  bf16 h = __float2bfloat16(v);
  return *(short*)&h;
}

// DPP quad-perm xor swaps (VALU pipe, vs ds_permute for __shfl_xor)
__device__ __forceinline__ float dppx1(float x) {  // lane ^ 1
  int r = __builtin_amdgcn_update_dpp(0, __builtin_bit_cast(int, x), 0xB1, 0xF, 0xF, true);
  return __builtin_bit_cast(float, r);
}
__device__ __forceinline__ float dppx2(float x) {  // lane ^ 2
  int r = __builtin_amdgcn_update_dpp(0, __builtin_bit_cast(int, x), 0x4E, 0xF, 0xF, true);
  return __builtin_bit_cast(float, r);
}

// -------- fused transpose + cast: W [K][N] f32 -> Wt [dstRow(n)][K] bf16 --------
// xf: 0 linear; 1 gate-interleave (row = (n>>6)*128 + (n&63)); 2 val (+64)
struct TJob { const float* src; bf16* dst; int K, N, base, xf; };
struct TTab { TJob j[9]; };

__global__ __launch_bounds__(256) void k_transpose_all(TTab tab) {
  __shared__ float tile[32][33];
  int blk = blockIdx.x;
  int ji = 0;
#pragma unroll
  for (int t = 1; t < 9; ++t) if (tab.j[t].base <= blk) ji = t;
  const float* W = tab.j[ji].src;
  bf16* Wt = tab.j[ji].dst;
  int K = tab.j[ji].K, N = tab.j[ji].N, xf = tab.j[ji].xf;
  int rel = blk - tab.j[ji].base;
  int nb = N >> 5;
  int n0 = (rel % nb) * 32, k0 = (rel / nb) * 32;
  int tx = threadIdx.x, ty = threadIdx.y;  // 32 x 8
#pragma unroll
  for (int r = ty; r < 32; r += 8) tile[r][tx] = W[(size_t)(k0 + r) * N + n0 + tx];
  __syncthreads();
#pragma unroll
  for (int r = ty; r < 32; r += 8) {
    int n = n0 + r;
    int drow = n;
    if (xf == 1) drow = ((n >> 6) << 7) + (n & 63);
    else if (xf == 2) drow = ((n >> 6) << 7) + (n & 63) + 64;
    Wt[(size_t)drow * K + k0 + tx] = __float2bfloat16(tile[tx][r]);
  }
}

// ---- fused: blocks [0,M) rmsnorm(x)->hF,hB ; blocks [M,2M) gather ae->aeF,aeB ----
__global__ __launch_bounds__(256) void k_pre(const float* __restrict__ x,
                                             const float* __restrict__ scale,
                                             float* __restrict__ hF, bf16* __restrict__ hB,
                                             const int* __restrict__ action,
                                             const float* __restrict__ embed,
                                             float* __restrict__ aeF, bf16* __restrict__ aeB) {
  int tid = threadIdx.x;
  if (blockIdx.x < M_) {
    int m = blockIdx.x;
    const float* row = x + (size_t)m * D_;
    float2 v = *(const float2*)(row + tid * 2);
    float ss = v.x * v.x + v.y * v.y;
#pragma unroll
    for (int o = 1; o < 64; o <<= 1) ss += __shfl_xor(ss, o);
    __shared__ float wsum[4];
    if ((tid & 63) == 0) wsum[tid >> 6] = ss;
    __syncthreads();
    float tot = wsum[0] + wsum[1] + wsum[2] + wsum[3];
    float rs = rsqrtf(tot * (1.0f / (float)D_) + EPS_);
    float2 sc = *(const float2*)(scale + tid * 2);
    float o0 = v.x * rs * sc.x, o1 = v.y * rs * sc.y;
    float2 o; o.x = o0; o.y = o1;
    *(float2*)(hF + (size_t)m * D_ + tid * 2) = o;
    bf16* p = hB + (size_t)m * D_ + tid * 2;
    p[0] = __float2bfloat16(o0); p[1] = __float2bfloat16(o1);
  } else {
    int m = blockIdx.x - M_;
    int a = action[m];
    float2 v = *(const float2*)(embed + (size_t)a * 512 + tid * 2);
    *(float2*)(aeF + (size_t)m * 512 + tid * 2) = v;
    bf16* p = aeB + (size_t)m * 512 + tid * 2;
    p[0] = __float2bfloat16(v.x); p[1] = __float2bfloat16(v.y);
  }
}

// ---------------- rmsnorm over D=512, optional f32 + bf16 outputs ----------------
__global__ __launch_bounds__(256) void k_rmsnorm(const float* __restrict__ x,
                                                 const float* __restrict__ scale,
                                                 float* __restrict__ outf,
                                                 bf16* __restrict__ outb) {
  int m = blockIdx.x, tid = threadIdx.x;
  const float* row = x + (size_t)m * D_;
  float2 v = *(const float2*)(row + tid * 2);
  float ss = v.x * v.x + v.y * v.y;
#pragma unroll
  for (int o = 1; o < 64; o <<= 1) ss += __shfl_xor(ss, o);
  __shared__ float wsum[4];
  if ((tid & 63) == 0) wsum[tid >> 6] = ss;
  __syncthreads();
  float tot = wsum[0] + wsum[1] + wsum[2] + wsum[3];
  float rs = rsqrtf(tot * (1.0f / (float)D_) + EPS_);
  float2 sc = *(const float2*)(scale + tid * 2);
  float o0 = v.x * rs * sc.x, o1 = v.y * rs * sc.y;
  if (outf) {
    float2 o; o.x = o0; o.y = o1;
    *(float2*)(outf + (size_t)m * D_ + tid * 2) = o;
  }
  if (outb) {
    bf16* p = outb + (size_t)m * D_ + tid * 2;
    p[0] = __float2bfloat16(o0); p[1] = __float2bfloat16(o1);
  }
}

// ---- beta = sigmoid(hF@wbeta), alpha = sigmoid(aeF@walpha) in one dispatch ----
__global__ __launch_bounds__(256) void k_dot8x2(const float* __restrict__ hF,
                                                const float* __restrict__ aeF,
                                                const float* __restrict__ W1,
                                                const float* __restrict__ W2,
                                                float* __restrict__ o1,
                                                float* __restrict__ o2) {
  int m = blockIdx.x, tid = threadIdx.x;
  float x0 = hF[(size_t)m * D_ + tid], x1 = hF[(size_t)m * D_ + 256 + tid];
  float y0 = aeF[(size_t)m * D_ + tid], y1 = aeF[(size_t)m * D_ + 256 + tid];
  float p[8], q[8];
#pragma unroll
  for (int j = 0; j < 8; ++j) {
    p[j] = x0 * W1[tid * 8 + j] + x1 * W1[(tid + 256) * 8 + j];
    q[j] = y0 * W2[tid * 8 + j] + y1 * W2[(tid + 256) * 8 + j];
  }
#pragma unroll
  for (int j = 0; j < 8; ++j) {
#pragma unroll
    for (int o = 1; o < 64; o <<= 1) {
      p[j] += __shfl_xor(p[j], o);
      q[j] += __shfl_xor(q[j], o);
    }
  }
  __shared__ float sacc[4][16];
  if ((tid & 63) == 0) {
#pragma unroll
    for (int j = 0; j < 8; ++j) { sacc[tid >> 6][j] = p[j]; sacc[tid >> 6][8 + j] = q[j]; }
  }
  __syncthreads();
  if (tid < 8) {
    float s = sacc[0][tid] + sacc[1][tid] + sacc[2][tid] + sacc[3][tid];
    o1[(size_t)m * 8 + tid] = sigmoidf_(s);
  } else if (tid < 16) {
    int j = tid - 8;
    float s = sacc[0][8 + j] + sacc[1][8 + j] + sacc[2][8 + j] + sacc[3][8 + j];
    o2[(size_t)m * 8 + j] = sigmoidf_(s);
  }
}

// ---- per (m,h): L2-normalize q,k in place; pack scal8 = {beta, g, kq, kbv, bvq} ----
__global__ __launch_bounds__(256) void k_qknorm_dots(float* __restrict__ qkv,
                                                     const float* __restrict__ buv,
                                                     const float* __restrict__ betaF,
                                                     const float* __restrict__ alphaF,
                                                     const int* __restrict__ mask,
                                                     float* __restrict__ scal8) {
  int blk = blockIdx.x * 4 + (threadIdx.x >> 6);
  int m = blk >> 3, h = blk & 7, t = threadIdx.x & 63;
  size_t qi = (size_t)m * 1536 + h * 64 + t;
  float q = qkv[qi], k = qkv[qi + 512];
  float bv = buv[(size_t)m * 1024 + 512 + h * 64 + t];
  float qs = q * q, ks = k * k;
#pragma unroll
  for (int o = 1; o < 64; o <<= 1) { qs += __shfl_xor(qs, o); ks += __shfl_xor(ks, o); }
  float qn = q / (sqrtf(qs) + EPS_);
  float kn = k / (sqrtf(ks) + EPS_);
  qkv[qi] = qn; qkv[qi + 512] = kn;
  float d0 = kn * qn, d1 = kn * bv, d2 = bv * qn;
#pragma unroll
  for (int o = 1; o < 64; o <<= 1) {
    d0 += __shfl_xor(d0, o); d1 += __shfl_xor(d1, o); d2 += __shfl_xor(d2, o);
  }
  if (t == 0) {
    int mh = m * 8 + h;
    float4 s4;
    s4.x = betaF[mh];
    s4.y = alphaF[mh] * (1.0f - (float)mask[m]);
    s4.z = d0; s4.w = d1;
    *(float4*)(scal8 + (size_t)mh * 8) = s4;
    scal8[(size_t)mh * 8 + 4] = d2;
  }
}

// ======== pipelined bf16 MFMA GEMM: C = epi(A[M,K] @ Bt[N,K]^T), 64x64 tile ========
template <int EPI>
__global__ __launch_bounds__(256) void k_gemm2(const bf16* __restrict__ A,
                                               const bf16* __restrict__ Bt,
                                               void* __restrict__ Cv, int M, int N, int K,
                                               int actSplit, const float* __restrict__ bias,
                                               const float* __restrict__ res) {
  __shared__ bf16 As[2][64 * 32];
  __shared__ bf16 Bs[2][64 * 32];
  const int tid = threadIdx.x;
  const int wave = tid >> 6, lane = tid & 63;
  const int wm = wave >> 1, wn = wave & 1;
  const int m0 = blockIdx.y * 64, n0 = blockIdx.x * 64;
  const int lr = lane & 15, lg = lane >> 4;
  const int srow = (wave << 4) | (lane >> 2);
  const int skb = (lane & 3) << 3;
  const bf16* ga = A + (size_t)(m0 + srow) * K + skb;
  const bf16* gb = Bt + (size_t)(n0 + srow) * K + skb;

  f32x4 acc[2][2];
#pragma unroll
  for (int i = 0; i < 2; ++i)
#pragma unroll
    for (int j = 0; j < 2; ++j) acc[i][j] = (f32x4){0.f, 0.f, 0.f, 0.f};

  const int nk = K >> 5;
  int4 ar = *(const int4*)ga;
  int4 br = *(const int4*)gb;
  for (int t = 0; t < nk; ++t) {
    bf16* asb = &As[t & 1][0];
    bf16* bsb = &Bs[t & 1][0];
    *(int4*)(asb + tid * 8) = ar;
    *(int4*)(bsb + tid * 8) = br;
    __syncthreads();
    if (t + 1 < nk) {
      ar = *(const int4*)(ga + ((size_t)(t + 1) << 5));
      br = *(const int4*)(gb + ((size_t)(t + 1) << 5));
    }
    bf16x8 af[2], bfr[2];
#pragma unroll
    for (int mm = 0; mm < 2; ++mm)
      af[mm] = *(const bf16x8*)(asb + (wm * 32 + mm * 16 + lr) * 32 + lg * 8);
#pragma unroll
    for (int nn = 0; nn < 2; ++nn)
      bfr[nn] = *(const bf16x8*)(bsb + (wn * 32 + nn * 16 + lr) * 32 + lg * 8);
#pragma unroll
    for (int mm = 0; mm < 2; ++mm)
#pragma unroll
      for (int nn = 0; nn < 2; ++nn)
        acc[mm][nn] = __builtin_amdgcn_mfma_f32_16x16x32_bf16(af[mm], bfr[nn], acc[mm][nn], 0, 0, 0);
  }

  float* C = (float*)Cv;
#pragma unroll
  for (int mm = 0; mm < 2; ++mm) {
#pragma unroll
    for (int nn = 0; nn < 2; ++nn) {
#pragma unroll
      for (int r = 0; r < 4; ++r) {
        int row = m0 + wm * 32 + mm * 16 + lg * 4 + r;
        int col = n0 + wn * 32 + nn * 16 + lr;
        float v = acc[mm][nn][r];
        if constexpr (EPI == 1) {
          if (col < actSplit) v = v * sigmoidf_(v);
        }
        if constexpr (EPI == 2) v += bias[col] + res[(size_t)row * N + col];
        if constexpr (EPI == 3) v += res[(size_t)row * N + col];
        C[(size_t)row * N + col] = v;
      }
    }
  }
}

// ======== 128x128-tile pipelined GEMM (8 waves): for the big GEMMs ========
template <int EPI>
__global__ __launch_bounds__(512) void k_gemm3(const bf16* __restrict__ A,
                                               const bf16* __restrict__ Bt,
                                               void* __restrict__ Cv, int M, int N, int K,
                                               int actSplit) {
  __shared__ bf16 As[2][128 * 32];
  __shared__ bf16 Bs[2][128 * 32];
  __shared__ float gateL[EPI == 4 ? 128 * 65 : 1];
  const int tid = threadIdx.x;
  const int wave = tid >> 6, lane = tid & 63;
  const int wm = wave >> 1, wn = wave & 1;
  const int m0 = blockIdx.y * 128, n0 = blockIdx.x * 128;
  const int lr = lane & 15, lg = lane >> 4;
  const int srow = tid >> 2, skb = (tid & 3) << 3;
  const bf16* ga = A + (size_t)(m0 + srow) * K + skb;
  const bf16* gb = Bt + (size_t)(n0 + srow) * K + skb;

  f32x4 acc[2][4];
#pragma unroll
  for (int i = 0; i < 2; ++i)
#pragma unroll
    for (int j = 0; j < 4; ++j) acc[i][j] = (f32x4){0.f, 0.f, 0.f, 0.f};

  const int nk = K >> 5;
  int4 ar = *(const int4*)ga;
  int4 br = *(const int4*)gb;
  for (int t = 0; t < nk; ++t) {
    bf16* asb = &As[t & 1][0];
    bf16* bsb = &Bs[t & 1][0];
    *(int4*)(asb + tid * 8) = ar;
    *(int4*)(bsb + tid * 8) = br;
    __syncthreads();
    if (t + 1 < nk) {
      ar = *(const int4*)(ga + ((size_t)(t + 1) << 5));
      br = *(const int4*)(gb + ((size_t)(t + 1) << 5));
    }
    bf16x8 af[2], bfr[4];
#pragma unroll
    for (int mm = 0; mm < 2; ++mm)
      af[mm] = *(const bf16x8*)(asb + (wm * 32 + mm * 16 + lr) * 32 + lg * 8);
#pragma unroll
    for (int nn = 0; nn < 4; ++nn)
      bfr[nn] = *(const bf16x8*)(bsb + (wn * 64 + nn * 16 + lr) * 32 + lg * 8);
#pragma unroll
    for (int mm = 0; mm < 2; ++mm)
#pragma unroll
      for (int nn = 0; nn < 4; ++nn)
        acc[mm][nn] = __builtin_amdgcn_mfma_f32_16x16x32_bf16(af[mm], bfr[nn], acc[mm][nn], 0, 0, 0);
  }

  if constexpr (EPI == 4) {
    __syncthreads();
    if (wn == 0) {
#pragma unroll
      for (int mm = 0; mm < 2; ++mm)
#pragma unroll
        for (int nn = 0; nn < 4; ++nn)
#pragma unroll
          for (int r = 0; r < 4; ++r)
            gateL[(wm * 32 + mm * 16 + lg * 4 + r) * 65 + nn * 16 + lr] = acc[mm][nn][r];
    }
    __syncthreads();
    if (wn == 1) {
      bf16* Cb = (bf16*)Cv;
#pragma unroll
      for (int mm = 0; mm < 2; ++mm)
#pragma unroll
        for (int nn = 0; nn < 4; ++nn)
#pragma unroll
          for (int r = 0; r < 4; ++r) {
            int row = wm * 32 + mm * 16 + lg * 4 + r;
            int vcol = nn * 16 + lr;
            float g = gateL[row * 65 + vcol];
            float v = acc[mm][nn][r];
            Cb[(size_t)(m0 + row) * 2048 + blockIdx.x * 64 + vcol] =
                __float2bfloat16(g * sigmoidf_(g) * v);
          }
    }
  } else {
    float* C = (float*)Cv;
#pragma unroll
    for (int mm = 0; mm < 2; ++mm) {
#pragma unroll
      for (int nn = 0; nn < 4; ++nn) {
#pragma unroll
        for (int r = 0; r < 4; ++r) {
          int row = m0 + wm * 32 + mm * 16 + lg * 4 + r;
          int col = n0 + wn * 64 + nn * 16 + lr;
          float v = acc[mm][nn][r];
          if constexpr (EPI == 1) {
            if (col < actSplit) v = v * sigmoidf_(v);
          }
          C[(size_t)row * N + col] = v;
        }
      }
    }
  }
}

// ================= chunked recurrence =================
// Per-step transition: hs' = hs @ A_t + U_t,  A_t = g (I - beta k k^T),
// U_t[i][j] = beta v_i k_j + bu_i (bv_j - beta*kbv*k_j).
// Scan thread layout: tid = 16*i + q16; thread owns cols [q16*4, q16*4+4) of row i.

// ---- phase 1: per-chunk transition (P^T bf16 hi/lo + U^T f32) + qtilde/utilde ----
// 1024 threads (16 waves) per chunk -> 8 waves/SIMD at 512-block grid.
__global__ __launch_bounds__(1024) void k_scan_chunk(
    const float* __restrict__ qkv, const float* __restrict__ buv,
    const float* __restrict__ scal8, bf16* __restrict__ PtHi,
    bf16* __restrict__ PtLo, float* __restrict__ Ut,
    float* __restrict__ Qtb, float* __restrict__ Vtb) {
  __shared__ float kL[CLEN_][64], qL[CLEN_][64], bvL[CLEN_][64];
  __shared__ float vL[CLEN_][64], buL[CLEN_][64];
  __shared__ float scL[CLEN_][8];
  const int blk = blockIdx.x, bh = blk >> 5, c = blk & (CHUNKS_ - 1);
  const int b = bh >> 3, h = bh & 7;
  const int tid = threadIdx.x, i = tid >> 4, q16 = tid & 15, j0 = q16 * 4;
  const bool writer = (q16 == 0);
  const int m0 = b * S_ + c * CLEN_;

  // cooperative stage (first 512 threads): thread -> (s = tid>>4, quad = (tid&15)*4)
  if (tid < 512) {
    int s = tid >> 4, fo = (tid & 15) * 4;
    const float* qb = qkv + (size_t)(m0 + s) * 1536 + h * 64;
    const float* bb = buv + (size_t)(m0 + s) * 1024 + h * 64;
    *(float4*)&qL[s][fo]  = *(const float4*)(qb + fo);
    *(float4*)&kL[s][fo]  = *(const float4*)(qb + 512 + fo);
    *(float4*)&vL[s][fo]  = *(const float4*)(qb + 1024 + fo);
    *(float4*)&buL[s][fo] = *(const float4*)(bb + fo);
    *(float4*)&bvL[s][fo] = *(const float4*)(bb + 512 + fo);
    if ((tid & 15) < 2)
      *(float4*)&scL[s][(tid & 1) * 4] =
          *(const float4*)(scal8 + (size_t)((m0 + s) * 8 + h) * 8 + (tid & 1) * 4);
  }
  __syncthreads();

  alignas(16) float P[4], U[4];
#pragma unroll
  for (int jj = 0; jj < 4; ++jj) { P[jj] = (j0 + jj == i) ? 1.f : 0.f; U[jj] = 0.f; }
  float* QT = Qtb + ((size_t)bh * CHUNKS_ + c) * (CLEN_ * 64);
  float* VT = Vtb + ((size_t)bh * CHUNKS_ + c) * (CLEN_ * 64);

  struct Step4 { float k[4], q[4], bv[4]; float v_i, bu_i, beta, g, kq, kbv, bvq; };
  auto LOAD = [&](Step4& sd, int s) {
    *(float4*)&sd.k[0]  = *(const float4*)&kL[s][j0];
    *(float4*)&sd.q[0]  = *(const float4*)&qL[s][j0];
    *(float4*)&sd.bv[0] = *(const float4*)&bvL[s][j0];
    sd.v_i = vL[s][i];
    sd.bu_i = buL[s][i];
    float4 s4 = *(const float4*)&scL[s][0];
    sd.beta = s4.x; sd.g = s4.y; sd.kq = s4.z; sd.kbv = s4.w;
    sd.bvq = scL[s][4];
  };
  auto STEP = [&](const Step4& sd, int s) {
    float Pk = 0.f, Uk = 0.f, Pq = 0.f, Uq = 0.f;
#pragma unroll
    for (int jj = 0; jj < 4; ++jj) {
      Pk += P[jj] * sd.k[jj]; Uk += U[jj] * sd.k[jj];
      Pq += P[jj] * sd.q[jj]; Uq += U[jj] * sd.q[jj];
    }
    Pk += dppx1(Pk); Uk += dppx1(Uk); Pq += dppx1(Pq); Uq += dppx1(Uq);
    Pk += dppx2(Pk); Uk += dppx2(Uk); Pq += dppx2(Pq); Uq += dppx2(Uq);
    Pk += __shfl_xor(Pk, 4); Uk += __shfl_xor(Uk, 4);
    Pq += __shfl_xor(Pq, 4); Uq += __shfl_xor(Uq, 4);
    Pk += __shfl_xor(Pk, 8); Uk += __shfl_xor(Uk, 8);
    Pq += __shfl_xor(Pq, 8); Uq += __shfl_xor(Uq, 8);
    float gb = sd.g * sd.beta;
    float cP = gb * Pk;
    float Ai = sd.beta * sd.v_i - gb * Uk - sd.bu_i * sd.beta * sd.kbv;
    if (writer) {
      QT[s * 64 + i] = sd.g * Pq - cP * sd.kq;
      VT[s * 64 + i] = sd.g * Uq + Ai * sd.kq + sd.bu_i * sd.bvq;
    }
#pragma unroll
    for (int jj = 0; jj < 4; ++jj) {
      P[jj] = sd.g * P[jj] - cP * sd.k[jj];
      U[jj] = sd.g * U[jj] + Ai * sd.k[jj] + sd.bu_i * sd.bv[jj];
    }
  };

  Step4 A, Bs;
  LOAD(A, 0);
  LOAD(Bs, 1);
  for (int s = 0; s < CLEN_; s += 2) {
    STEP(A, s);
    if (s + 2 < CLEN_) LOAD(A, s + 2);
    STEP(Bs, s + 1);
    if (s + 3 < CLEN_) LOAD(Bs, s + 3);
  }

  const size_t base = ((size_t)bh * CHUNKS_ + c) * 4096;
#pragma unroll
  for (int jj = 0; jj < 4; ++jj) {
    int j = j0 + jj;
    float pv = P[jj];
    float rem;
    short ph = bf_hi(pv, rem);
    short pl = bf_of(rem);
    ((short*)PtHi)[base + (size_t)j * 64 + i] = ph;
    ((short*)PtLo)[base + (size_t)j * 64 + i] = pl;
    Ut[base + (size_t)j * 64 + i] = U[jj];
  }
}

// ---- phase 2: barrier-free register-resident MFMA chain (round-12 proven shape:
// 64 blocks x 64 threads, 1 wave/SIMD, ~196 VGPR live set — do NOT wave-pack) ----
#define PREFETCH_(SET, CIDX)                                                     \
  {                                                                              \
    const size_t cbo_ = (size_t)(CIDX) * 4096;                                   \
    _Pragma("unroll") for (int mt = 0; mt < 4; ++mt) {                           \
      _Pragma("unroll") for (int ks = 0; ks < 2; ++ks) {                         \
        size_t off_ = cbo_ + (size_t)(16 * mt + lr) * 64 + ks * 32 + lg * 8;     \
        aH[SET][mt][ks] = *(const bf16x8*)(PH + off_);                           \
        aL[SET][mt][ks] = *(const bf16x8*)(PL + off_);                           \
      }                                                                          \
      _Pragma("unroll") for (int r = 0; r < 4; ++r)                              \
        u[SET][mt][r] = UB[cbo_ + (size_t)(16 * mt + 4 * lg + r) * 64 + col0 + lr]; \
    }                                                                            \
  }

#define CHAINSTEP_(SET, NSET, CIDX)                                              \
  {                                                                              \
    if ((CIDX) + 1 < CHUNKS_) PREFETCH_(NSET, (CIDX) + 1);                       \
    _Pragma("unroll") for (int mt = 0; mt < 4; ++mt)                             \
      _Pragma("unroll") for (int r = 0; r < 4; ++r)                              \
        HB[(size_t)(CIDX) * 4096 + (size_t)(16 * mt + 4 * lg + r) * 64 + col0 + lr] = st[mt][r]; \
    bf16x8 bH[2], bL[2];                                                         \
    _Pragma("unroll") for (int ks = 0; ks < 2; ++ks) {                           \
      _Pragma("unroll") for (int e = 0; e < 8; ++e) {                            \
        int src_ = (2 * (lg & 1) + (e >> 2)) * 16 + lr;                          \
        float va_ = __shfl(st[2 * ks][e & 3], src_);                             \
        float vb_ = __shfl(st[2 * ks + 1][e & 3], src_);                         \
        float bv_ = (lg & 2) ? vb_ : va_;                                        \
        float rem_;                                                              \
        bH[ks][e] = bf_hi(bv_, rem_);                                            \
        bL[ks][e] = bf_of(rem_);                                                 \
      }                                                                          \
    }                                                                            \
    f32x4 stn[4];                                                                \
    _Pragma("unroll") for (int mt = 0; mt < 4; ++mt) {                           \
      f32x4 a_ = u[SET][mt];                                                     \
      _Pragma("unroll") for (int ks = 0; ks < 2; ++ks) {                         \
        a_ = __builtin_amdgcn_mfma_f32_16x16x32_bf16(aH[SET][mt][ks], bH[ks], a_, 0, 0, 0); \
        a_ = __builtin_amdgcn_mfma_f32_16x16x32_bf16(aH[SET][mt][ks], bL[ks], a_, 0, 0, 0); \
        a_ = __builtin_amdgcn_mfma_f32_16x16x32_bf16(aL[SET][mt][ks], bH[ks], a_, 0, 0, 0); \
      }                                                                          \
      stn[mt] = a_;                                                              \
    }                                                                            \
    _Pragma("unroll") for (int mt = 0; mt < 4; ++mt) st[mt] = stn[mt];           \
  }

__global__ __launch_bounds__(64, 1) void k_chain3(
    const bf16* __restrict__ PtHi, const bf16* __restrict__ PtLo,
    const float* __restrict__ Ut, const float* __restrict__ carry,
    float* __restrict__ Hbuf, float* __restrict__ out_hs) {
  const int bh = blockIdx.x >> 2, cb = blockIdx.x & 3, col0 = cb * 16;
  const int lane = threadIdx.x & 63, lr = lane & 15, lg = lane >> 4;
  const short* PH = (const short*)PtHi + (size_t)bh * CHUNKS_ * 4096;
  const short* PL = (const short*)PtLo + (size_t)bh * CHUNKS_ * 4096;
  const float* UB = Ut + (size_t)bh * CHUNKS_ * 4096;
  float* HB = Hbuf + (size_t)bh * CHUNKS_ * 4096;

  f32x4 st[4];
#pragma unroll
  for (int mt = 0; mt < 4; ++mt)
    st[mt] = *(const f32x4*)(carry + ((size_t)bh * 64 + col0 + lr) * 64 + 16 * mt + 4 * lg);

  bf16x8 aH[2][4][2], aL[2][4][2];
  f32x4 u[2][4];
  PREFETCH_(0, 0);
  for (int c = 0; c < CHUNKS_; c += 2) {
    CHAINSTEP_(0, 1, c);
    CHAINSTEP_(1, 0, c + 1);
  }
#pragma unroll
  for (int mt = 0; mt < 4; ++mt)
    *(f32x4*)(out_hs + ((size_t)bh * 64 + col0 + lr) * 64 + 16 * mt + 4 * lg) = st[mt];
}

// ---- phase 3: Attn[64xCLEN] = H0 @ Qt^T + Vt per (bh, c), via hi/lo MFMA ----
__global__ __launch_bounds__(256) void k_attn_gemm(
    const float* __restrict__ Hbuf, const float* __restrict__ Qtb,
    const float* __restrict__ Vtb, float* __restrict__ attn) {
  const int blk = blockIdx.x, bh = blk >> 5, c = blk & (CHUNKS_ - 1);
  const int b = bh >> 3, h = bh & 7;
  const int tid = threadIdx.x, wave = tid >> 6, lane = tid & 63;
  const int lr = lane & 15, lg = lane >> 4;
  const float* H0 = Hbuf + ((size_t)bh * CHUNKS_ + c) * 4096;
  const float* QT = Qtb + ((size_t)bh * CHUNKS_ + c) * (CLEN_ * 64);
  const float* VT = Vtb + ((size_t)bh * CHUNKS_ + c) * (CLEN_ * 64);

  bf16x8 aH[2], aL[2];
#pragma unroll
  for (int ks = 0; ks < 2; ++ks) {
#pragma unroll
    for (int e = 0; e < 8; ++e) {
      float v = H0[(size_t)(ks * 32 + lg * 8 + e) * 64 + wave * 16 + lr];
      float rem;
      aH[ks][e] = bf_hi(v, rem);
      aL[ks][e] = bf_of(rem);
    }
  }
  f32x4 acc[2];
#pragma unroll
  for (int nt = 0; nt < 2; ++nt) {
    f32x4 a = (f32x4){0.f, 0.f, 0.f, 0.f};
#pragma unroll
    for (int ks = 0; ks < 2; ++ks) {
      const float* qp = QT + (size_t)(nt * 16 + lr) * 64 + ks * 32 + lg * 8;
      bf16x8 bH, bL;
#pragma unroll
      for (int e = 0; e < 8; ++e) {
        float rem;
        bH[e] = bf_hi(qp[e], rem);
        bL[e] = bf_of(rem);
      }
      a = __builtin_amdgcn_mfma_f32_16x16x32_bf16(aH[ks], bH, a, 0, 0, 0);
      a = __builtin_amdgcn_mfma_f32_16x16x32_bf16(aH[ks], bL, a, 0, 0, 0);
      a = __builtin_amdgcn_mfma_f32_16x16x32_bf16(aL[ks], bH, a, 0, 0, 0);
    }
    acc[nt] = a;
  }
  const int m0 = b * S_ + c * CLEN_;
#pragma unroll
  for (int nt = 0; nt < 2; ++nt) {
    int s = nt * 16 + lr;
    f32x4 vt = *(const f32x4*)(VT + (size_t)s * 64 + wave * 16 + lg * 4);
    f32x4 o = acc[nt];
#pragma unroll
    for (int r = 0; r < 4; ++r) o[r] += vt[r];
    *(f32x4*)(attn + (size_t)(m0 + s) * 512 + h * 64 + wave * 16 + lg * 4) = o;
  }
}

// ---------------- host ----------------
extern "C" void kernel_launch(void* const* d_in, const int* in_sizes, int n_in,
                              void* d_out, int out_size, void* d_ws, size_t ws_size,
                              hipStream_t stream) {
  const float* x      = (const float*)d_in[0];
  const int*   action = (const int*)d_in[1];
  const int*   mask   = (const int*)d_in[2];
  const float* carry  = (const float*)d_in[3];
  const float* n1s    = (const float*)d_in[4];
  const float* wq     = (const float*)d_in[5];
  const float* wk     = (const float*)d_in[6];
  const float* wv     = (const float*)d_in[7];
  const float* wbeta  = (const float*)d_in[8];
  const float* embed  = (const float*)d_in[9];
  const float* walpha = (const float*)d_in[10];
  const float* wbu    = (const float*)d_in[11];
  const float* wbv    = (const float*)d_in[12];
  const float* nas    = (const float*)d_in[13];
  const float* wout   = (const float*)d_in[14];
  const float* bout   = (const float*)d_in[15];
  const float* n2s    = (const float*)d_in[16];
  const float* wgate  = (const float*)d_in[17];
  const float* wval   = (const float*)d_in[18];
  const float* wffn   = (const float*)d_in[19];

  float* out_hs  = (float*)d_out;            // [2,8,64,64]
  float* out_ffn = (float*)d_out + 65536;    // [2,1024,512]

  char* p = (char*)d_ws;
  auto alloc = [&](size_t bytes) -> char* {
    char* r = p; p += (bytes + 255) & ~(size_t)255; return r;
  };
  bf16*  wqkvT = (bf16*)alloc((size_t)1536 * 512 * 2);
  bf16*  wbuvT = (bf16*)alloc((size_t)1024 * 512 * 2);
  bf16*  woutT = (bf16*)alloc((size_t)512 * 512 * 2);
  bf16*  wgvT  = (bf16*)alloc((size_t)4096 * 512 * 2);   // gate/val row-interleaved (128-groups)
  bf16*  wffnT = (bf16*)alloc((size_t)512 * 2048 * 2);
  float* qkvF  = (float*)alloc((size_t)M_ * 1536 * 4);
  float* buvF  = (float*)alloc((size_t)M_ * 1024 * 4);
  float* betaF = (float*)alloc((size_t)M_ * 8 * 4);
  float* alphaF= (float*)alloc((size_t)M_ * 8 * 4);
  float* scal8 = (float*)alloc((size_t)M_ * 8 * 8 * 4);
  float* attnF = (float*)alloc((size_t)M_ * 512 * 4);
  bf16*  attnB = (bf16*)alloc((size_t)M_ * 512 * 2);
  float* skipF = (float*)alloc((size_t)M_ * 512 * 4);
  bf16*  h2B   = (bf16*)alloc((size_t)M_ * 512 * 2);
  bf16*  ffnB  = (bf16*)alloc((size_t)M_ * 2048 * 2);
  char*  tail  = alloc((size_t)32 * 1024 * 1024);
  if ((size_t)(p - (char*)d_ws) > ws_size) return;  // workspace too small

  float* hF  = (float*)tail;                               // 4 MiB
  bf16*  hB  = (bf16*)(tail + ((size_t)4 << 20));          // 2 MiB
  float* aeF = (float*)(tail + ((size_t)6 << 20));         // 4 MiB
  bf16*  aeB = (bf16*)(tail + ((size_t)10 << 20));         // 2 MiB

  bf16*  PtHi = (bf16*)tail;                               // 4 MiB
  bf16*  PtLo = (bf16*)(tail + ((size_t)4 << 20));         // 4 MiB
  float* UtB  = (float*)(tail + ((size_t)8 << 20));        // 8 MiB
  float* Hbuf = (float*)(tail + ((size_t)16 << 20));       // 8 MiB
  float* Qtb  = (float*)(tail + ((size_t)24 << 20));       // 4 MiB
  float* Vtb  = (float*)(tail + ((size_t)28 << 20));       // 4 MiB

  TTab tab;
  tab.j[0] = {wq,    wqkvT,              512,  512,  0,    0};
  tab.j[1] = {wk,    wqkvT + 512 * 512,  512,  512,  256,  0};
  tab.j[2] = {wv,    wqkvT + 1024 * 512, 512,  512,  512,  0};
  tab.j[3] = {wbu,   wbuvT,              512,  512,  768,  0};
  tab.j[4] = {wbv,   wbuvT + 512 * 512,  512,  512,  1024, 0};
  tab.j[5] = {wout,  woutT,              512,  512,  1280, 0};
  tab.j[6] = {wgate, wgvT,               512,  2048, 1536, 1};
  tab.j[7] = {wval,  wgvT,               512,  2048, 2560, 2};
  tab.j[8] = {wffn,  wffnT,              2048, 512,  3584, 0};
  k_transpose_all<<<4608, dim3(32, 8), 0, stream>>>(tab);

  k_pre<<<M_ * 2, 256, 0, stream>>>(x, n1s, hF, hB, action, embed, aeF, aeB);

  k_gemm3<1><<<dim3(1536 / 128, M_ / 128), 512, 0, stream>>>(hB, wqkvT, qkvF, M_, 1536, 512, 1024);
  k_gemm2<0><<<dim3(1024 / 64, M_ / 64), 256, 0, stream>>>(aeB, wbuvT, buvF, M_, 1024, 512, 0, nullptr, nullptr);
  k_dot8x2<<<M_, 256, 0, stream>>>(hF, aeF, wbeta, walpha, betaF, alphaF);
  k_qknorm_dots<<<M_ * 2, 256, 0, stream>>>(qkvF, buvF, betaF, alphaF, mask, scal8);
  // hF/hB/aeF/aeB dead from here; tail region is reused by the chunk buffers.

  k_scan_chunk<<<16 * CHUNKS_, 1024, 0, stream>>>(qkvF, buvF, scal8, PtHi, PtLo, UtB, Qtb, Vtb);
  k_chain3<<<64, 64, 0, stream>>>(PtHi, PtLo, UtB, carry, Hbuf, out_hs);
  k_attn_gemm<<<16 * CHUNKS_, 256, 0, stream>>>(Hbuf, Qtb, Vtb, attnF);

  k_rmsnorm<<<M_, 256, 0, stream>>>(attnF, nas, nullptr, attnB);
  k_gemm2<2><<<dim3(512 / 64, M_ / 64), 256, 0, stream>>>(attnB, woutT, skipF, M_, 512, 512, 0, bout, x);
  k_rmsnorm<<<M_, 256, 0, stream>>>(skipF, n2s, nullptr, h2B);
  k_gemm3<4><<<dim3(4096 / 128, M_ / 128), 512, 0, stream>>>(h2B, wgvT, ffnB, M_, 4096, 512, 0);
  k_gemm2<3><<<dim3(512 / 64, M_ / 64), 256, 0, stream>>>(ffnB, wffnT, out_ffn, M_, 512, 2048, 0, nullptr, skipF);
}

// Round 16
// 187.567 us; speedup vs baseline: 1.0570x; 1.0570x over previous
//
#include <hip/hip_runtime.h>
#include <hip/hip_bf16.h>
#include <cstdint>
#include <cstddef>

using bf16 = __hip_bfloat16;
typedef __attribute__((ext_vector_type(8))) short bf16x8;  // 8 bf16 (4 VGPRs)
typedef __attribute__((ext_vector_type(4))) float f32x4;

static constexpr int B_ = 2, S_ = 1024, D_ = 512, H_ = 8;
static constexpr int M_ = B_ * S_;     // 2048 rows
static constexpr int CHUNKS_ = 32, CLEN_ = 32;  // S = CHUNKS * CLEN
static constexpr float EPS_ = 1e-6f;

__device__ __forceinline__ float sigmoidf_(float x) { return 1.0f / (1.0f + __expf(-x)); }

__device__ __forceinline__ short bf_hi(float v, float& rem) {
  bf16 h = __float2bfloat16(v);
  rem = v - __bfloat162float(h);
  return *(short*)&h;
}
__device__ __forceinline__ short bf_of(float v) {
  bf16 h = __float2bfloat16(v);
  return *(short*)&h;
}

// DPP quad-perm xor swaps (VALU pipe, vs ds_permute for __shfl_xor)
__device__ __forceinline__ float dppx1(float x) {  // lane ^ 1
  int r = __builtin_amdgcn_update_dpp(0, __builtin_bit_cast(int, x), 0xB1, 0xF, 0xF, true);
  return __builtin_bit_cast(float, r);
}
__device__ __forceinline__ float dppx2(float x) {  // lane ^ 2
  int r = __builtin_amdgcn_update_dpp(0, __builtin_bit_cast(int, x), 0x4E, 0xF, 0xF, true);
  return __builtin_bit_cast(float, r);
}

// -------- fused transpose + cast: W [K][N] f32 -> Wt [dstRow(n)][K] bf16 --------
// xf: 0 linear; 1 gate-interleave (row = (n>>6)*128 + (n&63)); 2 val (+64)
struct TJob { const float* src; bf16* dst; int K, N, base, xf; };
struct TTab { TJob j[9]; };

__global__ __launch_bounds__(256) void k_transpose_all(TTab tab) {
  __shared__ float tile[32][33];
  int blk = blockIdx.x;
  int ji = 0;
#pragma unroll
  for (int t = 1; t < 9; ++t) if (tab.j[t].base <= blk) ji = t;
  const float* W = tab.j[ji].src;
  bf16* Wt = tab.j[ji].dst;
  int K = tab.j[ji].K, N = tab.j[ji].N, xf = tab.j[ji].xf;
  int rel = blk - tab.j[ji].base;
  int nb = N >> 5;
  int n0 = (rel % nb) * 32, k0 = (rel / nb) * 32;
  int tx = threadIdx.x, ty = threadIdx.y;  // 32 x 8
#pragma unroll
  for (int r = ty; r < 32; r += 8) tile[r][tx] = W[(size_t)(k0 + r) * N + n0 + tx];
  __syncthreads();
#pragma unroll
  for (int r = ty; r < 32; r += 8) {
    int n = n0 + r;
    int drow = n;
    if (xf == 1) drow = ((n >> 6) << 7) + (n & 63);
    else if (xf == 2) drow = ((n >> 6) << 7) + (n & 63) + 64;
    Wt[(size_t)drow * K + k0 + tx] = __float2bfloat16(tile[tx][r]);
  }
}

// ---- fused: blocks [0,M) rmsnorm(x)->hF,hB ; blocks [M,2M) gather ae->aeF,aeB ----
__global__ __launch_bounds__(256) void k_pre(const float* __restrict__ x,
                                             const float* __restrict__ scale,
                                             float* __restrict__ hF, bf16* __restrict__ hB,
                                             const int* __restrict__ action,
                                             const float* __restrict__ embed,
                                             float* __restrict__ aeF, bf16* __restrict__ aeB) {
  int tid = threadIdx.x;
  if (blockIdx.x < M_) {
    int m = blockIdx.x;
    const float* row = x + (size_t)m * D_;
    float2 v = *(const float2*)(row + tid * 2);
    float ss = v.x * v.x + v.y * v.y;
#pragma unroll
    for (int o = 1; o < 64; o <<= 1) ss += __shfl_xor(ss, o);
    __shared__ float wsum[4];
    if ((tid & 63) == 0) wsum[tid >> 6] = ss;
    __syncthreads();
    float tot = wsum[0] + wsum[1] + wsum[2] + wsum[3];
    float rs = rsqrtf(tot * (1.0f / (float)D_) + EPS_);
    float2 sc = *(const float2*)(scale + tid * 2);
    float o0 = v.x * rs * sc.x, o1 = v.y * rs * sc.y;
    float2 o; o.x = o0; o.y = o1;
    *(float2*)(hF + (size_t)m * D_ + tid * 2) = o;
    bf16* p = hB + (size_t)m * D_ + tid * 2;
    p[0] = __float2bfloat16(o0); p[1] = __float2bfloat16(o1);
  } else {
    int m = blockIdx.x - M_;
    int a = action[m];
    float2 v = *(const float2*)(embed + (size_t)a * 512 + tid * 2);
    *(float2*)(aeF + (size_t)m * 512 + tid * 2) = v;
    bf16* p = aeB + (size_t)m * 512 + tid * 2;
    p[0] = __float2bfloat16(v.x); p[1] = __float2bfloat16(v.y);
  }
}

// ---------------- rmsnorm over D=512, optional f32 + bf16 outputs ----------------
__global__ __launch_bounds__(256) void k_rmsnorm(const float* __restrict__ x,
                                                 const float* __restrict__ scale,
                                                 float* __restrict__ outf,
                                                 bf16* __restrict__ outb) {
  int m = blockIdx.x, tid = threadIdx.x;
  const float* row = x + (size_t)m * D_;
  float2 v = *(const float2*)(row + tid * 2);
  float ss = v.x * v.x + v.y * v.y;
#pragma unroll
  for (int o = 1; o < 64; o <<= 1) ss += __shfl_xor(ss, o);
  __shared__ float wsum[4];
  if ((tid & 63) == 0) wsum[tid >> 6] = ss;
  __syncthreads();
  float tot = wsum[0] + wsum[1] + wsum[2] + wsum[3];
  float rs = rsqrtf(tot * (1.0f / (float)D_) + EPS_);
  float2 sc = *(const float2*)(scale + tid * 2);
  float o0 = v.x * rs * sc.x, o1 = v.y * rs * sc.y;
  if (outf) {
    float2 o; o.x = o0; o.y = o1;
    *(float2*)(outf + (size_t)m * D_ + tid * 2) = o;
  }
  if (outb) {
    bf16* p = outb + (size_t)m * D_ + tid * 2;
    p[0] = __float2bfloat16(o0); p[1] = __float2bfloat16(o1);
  }
}

// ---- beta = sigmoid(hF@wbeta), alpha = sigmoid(aeF@walpha) in one dispatch ----
__global__ __launch_bounds__(256) void k_dot8x2(const float* __restrict__ hF,
                                                const float* __restrict__ aeF,
                                                const float* __restrict__ W1,
                                                const float* __restrict__ W2,
                                                float* __restrict__ o1,
                                                float* __restrict__ o2) {
  int m = blockIdx.x, tid = threadIdx.x;
  float x0 = hF[(size_t)m * D_ + tid], x1 = hF[(size_t)m * D_ + 256 + tid];
  float y0 = aeF[(size_t)m * D_ + tid], y1 = aeF[(size_t)m * D_ + 256 + tid];
  float p[8], q[8];
#pragma unroll
  for (int j = 0; j < 8; ++j) {
    p[j] = x0 * W1[tid * 8 + j] + x1 * W1[(tid + 256) * 8 + j];
    q[j] = y0 * W2[tid * 8 + j] + y1 * W2[(tid + 256) * 8 + j];
  }
#pragma unroll
  for (int j = 0; j < 8; ++j) {
#pragma unroll
    for (int o = 1; o < 64; o <<= 1) {
      p[j] += __shfl_xor(p[j], o);
      q[j] += __shfl_xor(q[j], o);
    }
  }
  __shared__ float sacc[4][16];
  if ((tid & 63) == 0) {
#pragma unroll
    for (int j = 0; j < 8; ++j) { sacc[tid >> 6][j] = p[j]; sacc[tid >> 6][8 + j] = q[j]; }
  }
  __syncthreads();
  if (tid < 8) {
    float s = sacc[0][tid] + sacc[1][tid] + sacc[2][tid] + sacc[3][tid];
    o1[(size_t)m * 8 + tid] = sigmoidf_(s);
  } else if (tid < 16) {
    int j = tid - 8;
    float s = sacc[0][8 + j] + sacc[1][8 + j] + sacc[2][8 + j] + sacc[3][8 + j];
    o2[(size_t)m * 8 + j] = sigmoidf_(s);
  }
}

// ---- per (m,h): L2-normalize q,k in place; pack scal8 = {beta, g, kq, kbv, bvq} ----
__global__ __launch_bounds__(256) void k_qknorm_dots(float* __restrict__ qkv,
                                                     const float* __restrict__ buv,
                                                     const float* __restrict__ betaF,
                                                     const float* __restrict__ alphaF,
                                                     const int* __restrict__ mask,
                                                     float* __restrict__ scal8) {
  int blk = blockIdx.x * 4 + (threadIdx.x >> 6);
  int m = blk >> 3, h = blk & 7, t = threadIdx.x & 63;
  size_t qi = (size_t)m * 1536 + h * 64 + t;
  float q = qkv[qi], k = qkv[qi + 512];
  float bv = buv[(size_t)m * 1024 + 512 + h * 64 + t];
  float qs = q * q, ks = k * k;
#pragma unroll
  for (int o = 1; o < 64; o <<= 1) { qs += __shfl_xor(qs, o); ks += __shfl_xor(ks, o); }
  float qn = q / (sqrtf(qs) + EPS_);
  float kn = k / (sqrtf(ks) + EPS_);
  qkv[qi] = qn; qkv[qi + 512] = kn;
  float d0 = kn * qn, d1 = kn * bv, d2 = bv * qn;
#pragma unroll
  for (int o = 1; o < 64; o <<= 1) {
    d0 += __shfl_xor(d0, o); d1 += __shfl_xor(d1, o); d2 += __shfl_xor(d2, o);
  }
  if (t == 0) {
    int mh = m * 8 + h;
    float4 s4;
    s4.x = betaF[mh];
    s4.y = alphaF[mh] * (1.0f - (float)mask[m]);
    s4.z = d0; s4.w = d1;
    *(float4*)(scal8 + (size_t)mh * 8) = s4;
    scal8[(size_t)mh * 8 + 4] = d2;
  }
}

// ======== pipelined bf16 MFMA GEMM: C = epi(A[M,K] @ Bt[N,K]^T), 64x64 tile ========
template <int EPI>
__global__ __launch_bounds__(256) void k_gemm2(const bf16* __restrict__ A,
                                               const bf16* __restrict__ Bt,
                                               void* __restrict__ Cv, int M, int N, int K,
                                               int actSplit, const float* __restrict__ bias,
                                               const float* __restrict__ res) {
  __shared__ bf16 As[2][64 * 32];
  __shared__ bf16 Bs[2][64 * 32];
  const int tid = threadIdx.x;
  const int wave = tid >> 6, lane = tid & 63;
  const int wm = wave >> 1, wn = wave & 1;
  const int m0 = blockIdx.y * 64, n0 = blockIdx.x * 64;
  const int lr = lane & 15, lg = lane >> 4;
  const int srow = (wave << 4) | (lane >> 2);
  const int skb = (lane & 3) << 3;
  const bf16* ga = A + (size_t)(m0 + srow) * K + skb;
  const bf16* gb = Bt + (size_t)(n0 + srow) * K + skb;

  f32x4 acc[2][2];
#pragma unroll
  for (int i = 0; i < 2; ++i)
#pragma unroll
    for (int j = 0; j < 2; ++j) acc[i][j] = (f32x4){0.f, 0.f, 0.f, 0.f};

  const int nk = K >> 5;
  int4 ar = *(const int4*)ga;
  int4 br = *(const int4*)gb;
  for (int t = 0; t < nk; ++t) {
    bf16* asb = &As[t & 1][0];
    bf16* bsb = &Bs[t & 1][0];
    *(int4*)(asb + tid * 8) = ar;
    *(int4*)(bsb + tid * 8) = br;
    __syncthreads();
    if (t + 1 < nk) {
      ar = *(const int4*)(ga + ((size_t)(t + 1) << 5));
      br = *(const int4*)(gb + ((size_t)(t + 1) << 5));
    }
    bf16x8 af[2], bfr[2];
#pragma unroll
    for (int mm = 0; mm < 2; ++mm)
      af[mm] = *(const bf16x8*)(asb + (wm * 32 + mm * 16 + lr) * 32 + lg * 8);
#pragma unroll
    for (int nn = 0; nn < 2; ++nn)
      bfr[nn] = *(const bf16x8*)(bsb + (wn * 32 + nn * 16 + lr) * 32 + lg * 8);
#pragma unroll
    for (int mm = 0; mm < 2; ++mm)
#pragma unroll
      for (int nn = 0; nn < 2; ++nn)
        acc[mm][nn] = __builtin_amdgcn_mfma_f32_16x16x32_bf16(af[mm], bfr[nn], acc[mm][nn], 0, 0, 0);
  }

  float* C = (float*)Cv;
#pragma unroll
  for (int mm = 0; mm < 2; ++mm) {
#pragma unroll
    for (int nn = 0; nn < 2; ++nn) {
#pragma unroll
      for (int r = 0; r < 4; ++r) {
        int row = m0 + wm * 32 + mm * 16 + lg * 4 + r;
        int col = n0 + wn * 32 + nn * 16 + lr;
        float v = acc[mm][nn][r];
        if constexpr (EPI == 1) {
          if (col < actSplit) v = v * sigmoidf_(v);
        }
        if constexpr (EPI == 2) v += bias[col] + res[(size_t)row * N + col];
        if constexpr (EPI == 3) v += res[(size_t)row * N + col];
        C[(size_t)row * N + col] = v;
      }
    }
  }
}

// ======== 128x128-tile pipelined GEMM (8 waves): for the big GEMMs ========
template <int EPI>
__global__ __launch_bounds__(512) void k_gemm3(const bf16* __restrict__ A,
                                               const bf16* __restrict__ Bt,
                                               void* __restrict__ Cv, int M, int N, int K,
                                               int actSplit) {
  __shared__ bf16 As[2][128 * 32];
  __shared__ bf16 Bs[2][128 * 32];
  __shared__ float gateL[EPI == 4 ? 128 * 65 : 1];
  const int tid = threadIdx.x;
  const int wave = tid >> 6, lane = tid & 63;
  const int wm = wave >> 1, wn = wave & 1;
  const int m0 = blockIdx.y * 128, n0 = blockIdx.x * 128;
  const int lr = lane & 15, lg = lane >> 4;
  const int srow = tid >> 2, skb = (tid & 3) << 3;
  const bf16* ga = A + (size_t)(m0 + srow) * K + skb;
  const bf16* gb = Bt + (size_t)(n0 + srow) * K + skb;

  f32x4 acc[2][4];
#pragma unroll
  for (int i = 0; i < 2; ++i)
#pragma unroll
    for (int j = 0; j < 4; ++j) acc[i][j] = (f32x4){0.f, 0.f, 0.f, 0.f};

  const int nk = K >> 5;
  int4 ar = *(const int4*)ga;
  int4 br = *(const int4*)gb;
  for (int t = 0; t < nk; ++t) {
    bf16* asb = &As[t & 1][0];
    bf16* bsb = &Bs[t & 1][0];
    *(int4*)(asb + tid * 8) = ar;
    *(int4*)(bsb + tid * 8) = br;
    __syncthreads();
    if (t + 1 < nk) {
      ar = *(const int4*)(ga + ((size_t)(t + 1) << 5));
      br = *(const int4*)(gb + ((size_t)(t + 1) << 5));
    }
    bf16x8 af[2], bfr[4];
#pragma unroll
    for (int mm = 0; mm < 2; ++mm)
      af[mm] = *(const bf16x8*)(asb + (wm * 32 + mm * 16 + lr) * 32 + lg * 8);
#pragma unroll
    for (int nn = 0; nn < 4; ++nn)
      bfr[nn] = *(const bf16x8*)(bsb + (wn * 64 + nn * 16 + lr) * 32 + lg * 8);
#pragma unroll
    for (int mm = 0; mm < 2; ++mm)
#pragma unroll
      for (int nn = 0; nn < 4; ++nn)
        acc[mm][nn] = __builtin_amdgcn_mfma_f32_16x16x32_bf16(af[mm], bfr[nn], acc[mm][nn], 0, 0, 0);
  }

  if constexpr (EPI == 4) {
    __syncthreads();
    if (wn == 0) {
#pragma unroll
      for (int mm = 0; mm < 2; ++mm)
#pragma unroll
        for (int nn = 0; nn < 4; ++nn)
#pragma unroll
          for (int r = 0; r < 4; ++r)
            gateL[(wm * 32 + mm * 16 + lg * 4 + r) * 65 + nn * 16 + lr] = acc[mm][nn][r];
    }
    __syncthreads();
    if (wn == 1) {
      bf16* Cb = (bf16*)Cv;
#pragma unroll
      for (int mm = 0; mm < 2; ++mm)
#pragma unroll
        for (int nn = 0; nn < 4; ++nn)
#pragma unroll
          for (int r = 0; r < 4; ++r) {
            int row = wm * 32 + mm * 16 + lg * 4 + r;
            int vcol = nn * 16 + lr;
            float g = gateL[row * 65 + vcol];
            float v = acc[mm][nn][r];
            Cb[(size_t)(m0 + row) * 2048 + blockIdx.x * 64 + vcol] =
                __float2bfloat16(g * sigmoidf_(g) * v);
          }
    }
  } else {
    float* C = (float*)Cv;
#pragma unroll
    for (int mm = 0; mm < 2; ++mm) {
#pragma unroll
      for (int nn = 0; nn < 4; ++nn) {
#pragma unroll
        for (int r = 0; r < 4; ++r) {
          int row = m0 + wm * 32 + mm * 16 + lg * 4 + r;
          int col = n0 + wn * 64 + nn * 16 + lr;
          float v = acc[mm][nn][r];
          if constexpr (EPI == 1) {
            if (col < actSplit) v = v * sigmoidf_(v);
          }
          C[(size_t)row * N + col] = v;
        }
      }
    }
  }
}

// ================= chunked recurrence =================
// Per-step transition: hs' = hs @ A_t + U_t,  A_t = g (I - beta k k^T),
// U_t[i][j] = beta v_i k_j + bu_i (bv_j - beta*kbv*k_j).
// Scan thread layout: tid = 8*i + q8; thread owns cols [q8*8, q8*8+8) of row i.

// ---- phase 1: per-chunk transition (P^T bf16 hi/lo + U^T f32) + qtilde/utilde ----
__global__ __launch_bounds__(512) void k_scan_chunk(
    const float* __restrict__ qkv, const float* __restrict__ buv,
    const float* __restrict__ scal8, bf16* __restrict__ PtHi,
    bf16* __restrict__ PtLo, float* __restrict__ Ut,
    float* __restrict__ Qtb, float* __restrict__ Vtb) {
  __shared__ float kL[CLEN_][64], qL[CLEN_][64], bvL[CLEN_][64];
  __shared__ float vL[CLEN_][64], buL[CLEN_][64];
  __shared__ float scL[CLEN_][8];
  const int blk = blockIdx.x, bh = blk >> 5, c = blk & (CHUNKS_ - 1);
  const int b = bh >> 3, h = bh & 7;
  const int tid = threadIdx.x, i = tid >> 3, q8 = tid & 7, j0 = q8 * 8;
  const bool writer = (q8 == 0);
  const int m0 = b * S_ + c * CLEN_;

  {
    int s = tid >> 4, fo = (tid & 15) * 4;
    const float* qb = qkv + (size_t)(m0 + s) * 1536 + h * 64;
    const float* bb = buv + (size_t)(m0 + s) * 1024 + h * 64;
    *(float4*)&qL[s][fo]  = *(const float4*)(qb + fo);
    *(float4*)&kL[s][fo]  = *(const float4*)(qb + 512 + fo);
    *(float4*)&vL[s][fo]  = *(const float4*)(qb + 1024 + fo);
    *(float4*)&buL[s][fo] = *(const float4*)(bb + fo);
    *(float4*)&bvL[s][fo] = *(const float4*)(bb + 512 + fo);
    if ((tid & 15) < 2)
      *(float4*)&scL[s][(tid & 1) * 4] =
          *(const float4*)(scal8 + (size_t)((m0 + s) * 8 + h) * 8 + (tid & 1) * 4);
  }
  __syncthreads();

  alignas(16) float P[8], U[8];
#pragma unroll
  for (int jj = 0; jj < 8; ++jj) { P[jj] = (j0 + jj == i) ? 1.f : 0.f; U[jj] = 0.f; }
  float* QT = Qtb + ((size_t)bh * CHUNKS_ + c) * (CLEN_ * 64);
  float* VT = Vtb + ((size_t)bh * CHUNKS_ + c) * (CLEN_ * 64);

  struct Step8 { float k[8], q[8], bv[8]; float v_i, bu_i, beta, g, kq, kbv, bvq; };
  auto LOAD = [&](Step8& sd, int s) {
    *(float4*)&sd.k[0]  = *(const float4*)&kL[s][j0];
    *(float4*)&sd.k[4]  = *(const float4*)&kL[s][j0 + 4];
    *(float4*)&sd.q[0]  = *(const float4*)&qL[s][j0];
    *(float4*)&sd.q[4]  = *(const float4*)&qL[s][j0 + 4];
    *(float4*)&sd.bv[0] = *(const float4*)&bvL[s][j0];
    *(float4*)&sd.bv[4] = *(const float4*)&bvL[s][j0 + 4];
    sd.v_i = vL[s][i];
    sd.bu_i = buL[s][i];
    float4 s4 = *(const float4*)&scL[s][0];
    sd.beta = s4.x; sd.g = s4.y; sd.kq = s4.z; sd.kbv = s4.w;
    sd.bvq = scL[s][4];
  };
  auto STEP = [&](const Step8& sd, int s) {
    float Pk = 0.f, Uk = 0.f, Pq = 0.f, Uq = 0.f;
#pragma unroll
    for (int jj = 0; jj < 8; ++jj) {
      Pk += P[jj] * sd.k[jj]; Uk += U[jj] * sd.k[jj];
      Pq += P[jj] * sd.q[jj]; Uq += U[jj] * sd.q[jj];
    }
    Pk += dppx1(Pk); Uk += dppx1(Uk); Pq += dppx1(Pq); Uq += dppx1(Uq);
    Pk += dppx2(Pk); Uk += dppx2(Uk); Pq += dppx2(Pq); Uq += dppx2(Uq);
    Pk += __shfl_xor(Pk, 4); Uk += __shfl_xor(Uk, 4);
    Pq += __shfl_xor(Pq, 4); Uq += __shfl_xor(Uq, 4);
    float gb = sd.g * sd.beta;
    float cP = gb * Pk;
    float Ai = sd.beta * sd.v_i - gb * Uk - sd.bu_i * sd.beta * sd.kbv;
    if (writer) {
      QT[s * 64 + i] = sd.g * Pq - cP * sd.kq;
      VT[s * 64 + i] = sd.g * Uq + Ai * sd.kq + sd.bu_i * sd.bvq;
    }
#pragma unroll
    for (int jj = 0; jj < 8; ++jj) {
      P[jj] = sd.g * P[jj] - cP * sd.k[jj];
      U[jj] = sd.g * U[jj] + Ai * sd.k[jj] + sd.bu_i * sd.bv[jj];
    }
  };

  Step8 A, Bs;
  LOAD(A, 0);
  LOAD(Bs, 1);
  for (int s = 0; s < CLEN_; s += 2) {
    STEP(A, s);
    if (s + 2 < CLEN_) LOAD(A, s + 2);
    STEP(Bs, s + 1);
    if (s + 3 < CLEN_) LOAD(Bs, s + 3);
  }

  const size_t base = ((size_t)bh * CHUNKS_ + c) * 4096;
#pragma unroll
  for (int jj = 0; jj < 8; ++jj) {
    int j = j0 + jj;
    float pv = P[jj];
    float rem;
    short ph = bf_hi(pv, rem);
    short pl = bf_of(rem);
    ((short*)PtHi)[base + (size_t)j * 64 + i] = ph;
    ((short*)PtLo)[base + (size_t)j * 64 + i] = pl;
    Ut[base + (size_t)j * 64 + i] = U[jj];
  }
}

// ---- phase 2: barrier-free register-resident MFMA chain (round-12 proven shape:
// 64 blocks x 64 threads, 1 wave/SIMD, ~196 VGPR live set — do NOT wave-pack) ----
#define PREFETCH_(SET, CIDX)                                                     \
  {                                                                              \
    const size_t cbo_ = (size_t)(CIDX) * 4096;                                   \
    _Pragma("unroll") for (int mt = 0; mt < 4; ++mt) {                           \
      _Pragma("unroll") for (int ks = 0; ks < 2; ++ks) {                         \
        size_t off_ = cbo_ + (size_t)(16 * mt + lr) * 64 + ks * 32 + lg * 8;     \
        aH[SET][mt][ks] = *(const bf16x8*)(PH + off_);                           \
        aL[SET][mt][ks] = *(const bf16x8*)(PL + off_);                           \
      }                                                                          \
      _Pragma("unroll") for (int r = 0; r < 4; ++r)                              \
        u[SET][mt][r] = UB[cbo_ + (size_t)(16 * mt + 4 * lg + r) * 64 + col0 + lr]; \
    }                                                                            \
  }

#define CHAINSTEP_(SET, NSET, CIDX)                                              \
  {                                                                              \
    if ((CIDX) + 1 < CHUNKS_) PREFETCH_(NSET, (CIDX) + 1);                       \
    _Pragma("unroll") for (int mt = 0; mt < 4; ++mt)                             \
      _Pragma("unroll") for (int r = 0; r < 4; ++r)                              \
        HB[(size_t)(CIDX) * 4096 + (size_t)(16 * mt + 4 * lg + r) * 64 + col0 + lr] = st[mt][r]; \
    bf16x8 bH[2], bL[2];                                                         \
    _Pragma("unroll") for (int ks = 0; ks < 2; ++ks) {                           \
      _Pragma("unroll") for (int e = 0; e < 8; ++e) {                            \
        int src_ = (2 * (lg & 1) + (e >> 2)) * 16 + lr;                          \
        float va_ = __shfl(st[2 * ks][e & 3], src_);                             \
        float vb_ = __shfl(st[2 * ks + 1][e & 3], src_);                         \
        float bv_ = (lg & 2) ? vb_ : va_;                                        \
        float rem_;                                                              \
        bH[ks][e] = bf_hi(bv_, rem_);                                            \
        bL[ks][e] = bf_of(rem_);                                                 \
      }                                                                          \
    }                                                                            \
    f32x4 stn[4];                                                                \
    _Pragma("unroll") for (int mt = 0; mt < 4; ++mt) {                           \
      f32x4 a_ = u[SET][mt];                                                     \
      _Pragma("unroll") for (int ks = 0; ks < 2; ++ks) {                         \
        a_ = __builtin_amdgcn_mfma_f32_16x16x32_bf16(aH[SET][mt][ks], bH[ks], a_, 0, 0, 0); \
        a_ = __builtin_amdgcn_mfma_f32_16x16x32_bf16(aH[SET][mt][ks], bL[ks], a_, 0, 0, 0); \
        a_ = __builtin_amdgcn_mfma_f32_16x16x32_bf16(aL[SET][mt][ks], bH[ks], a_, 0, 0, 0); \
      }                                                                          \
      stn[mt] = a_;                                                              \
    }                                                                            \
    _Pragma("unroll") for (int mt = 0; mt < 4; ++mt) st[mt] = stn[mt];           \
  }

__global__ __launch_bounds__(64, 1) void k_chain3(
    const bf16* __restrict__ PtHi, const bf16* __restrict__ PtLo,
    const float* __restrict__ Ut, const float* __restrict__ carry,
    float* __restrict__ Hbuf, float* __restrict__ out_hs) {
  const int bh = blockIdx.x >> 2, cb = blockIdx.x & 3, col0 = cb * 16;
  const int lane = threadIdx.x & 63, lr = lane & 15, lg = lane >> 4;
  const short* PH = (const short*)PtHi + (size_t)bh * CHUNKS_ * 4096;
  const short* PL = (const short*)PtLo + (size_t)bh * CHUNKS_ * 4096;
  const float* UB = Ut + (size_t)bh * CHUNKS_ * 4096;
  float* HB = Hbuf + (size_t)bh * CHUNKS_ * 4096;

  f32x4 st[4];
#pragma unroll
  for (int mt = 0; mt < 4; ++mt)
    st[mt] = *(const f32x4*)(carry + ((size_t)bh * 64 + col0 + lr) * 64 + 16 * mt + 4 * lg);

  bf16x8 aH[2][4][2], aL[2][4][2];
  f32x4 u[2][4];
  PREFETCH_(0, 0);
  for (int c = 0; c < CHUNKS_; c += 2) {
    CHAINSTEP_(0, 1, c);
    CHAINSTEP_(1, 0, c + 1);
  }
#pragma unroll
  for (int mt = 0; mt < 4; ++mt)
    *(f32x4*)(out_hs + ((size_t)bh * 64 + col0 + lr) * 64 + 16 * mt + 4 * lg) = st[mt];
}

// ---- phase 3: Attn[64xCLEN] = H0 @ Qt^T + Vt per (bh, c), via hi/lo MFMA ----
__global__ __launch_bounds__(256) void k_attn_gemm(
    const float* __restrict__ Hbuf, const float* __restrict__ Qtb,
    const float* __restrict__ Vtb, float* __restrict__ attn) {
  const int blk = blockIdx.x, bh = blk >> 5, c = blk & (CHUNKS_ - 1);
  const int b = bh >> 3, h = bh & 7;
  const int tid = threadIdx.x, wave = tid >> 6, lane = tid & 63;
  const int lr = lane & 15, lg = lane >> 4;
  const float* H0 = Hbuf + ((size_t)bh * CHUNKS_ + c) * 4096;
  const float* QT = Qtb + ((size_t)bh * CHUNKS_ + c) * (CLEN_ * 64);
  const float* VT = Vtb + ((size_t)bh * CHUNKS_ + c) * (CLEN_ * 64);

  bf16x8 aH[2], aL[2];
#pragma unroll
  for (int ks = 0; ks < 2; ++ks) {
#pragma unroll
    for (int e = 0; e < 8; ++e) {
      float v = H0[(size_t)(ks * 32 + lg * 8 + e) * 64 + wave * 16 + lr];
      float rem;
      aH[ks][e] = bf_hi(v, rem);
      aL[ks][e] = bf_of(rem);
    }
  }
  f32x4 acc[2];
#pragma unroll
  for (int nt = 0; nt < 2; ++nt) {
    f32x4 a = (f32x4){0.f, 0.f, 0.f, 0.f};
#pragma unroll
    for (int ks = 0; ks < 2; ++ks) {
      const float* qp = QT + (size_t)(nt * 16 + lr) * 64 + ks * 32 + lg * 8;
      bf16x8 bH, bL;
#pragma unroll
      for (int e = 0; e < 8; ++e) {
        float rem;
        bH[e] = bf_hi(qp[e], rem);
        bL[e] = bf_of(rem);
      }
      a = __builtin_amdgcn_mfma_f32_16x16x32_bf16(aH[ks], bH, a, 0, 0, 0);
      a = __builtin_amdgcn_mfma_f32_16x16x32_bf16(aH[ks], bL, a, 0, 0, 0);
      a = __builtin_amdgcn_mfma_f32_16x16x32_bf16(aL[ks], bH, a, 0, 0, 0);
    }
    acc[nt] = a;
  }
  const int m0 = b * S_ + c * CLEN_;
#pragma unroll
  for (int nt = 0; nt < 2; ++nt) {
    int s = nt * 16 + lr;
    f32x4 vt = *(const f32x4*)(VT + (size_t)s * 64 + wave * 16 + lg * 4);
    f32x4 o = acc[nt];
#pragma unroll
    for (int r = 0; r < 4; ++r) o[r] += vt[r];
    *(f32x4*)(attn + (size_t)(m0 + s) * 512 + h * 64 + wave * 16 + lg * 4) = o;
  }
}

// ---------------- host ----------------
extern "C" void kernel_launch(void* const* d_in, const int* in_sizes, int n_in,
                              void* d_out, int out_size, void* d_ws, size_t ws_size,
                              hipStream_t stream) {
  const float* x      = (const float*)d_in[0];
  const int*   action = (const int*)d_in[1];
  const int*   mask   = (const int*)d_in[2];
  const float* carry  = (const float*)d_in[3];
  const float* n1s    = (const float*)d_in[4];
  const float* wq     = (const float*)d_in[5];
  const float* wk     = (const float*)d_in[6];
  const float* wv     = (const float*)d_in[7];
  const float* wbeta  = (const float*)d_in[8];
  const float* embed  = (const float*)d_in[9];
  const float* walpha = (const float*)d_in[10];
  const float* wbu    = (const float*)d_in[11];
  const float* wbv    = (const float*)d_in[12];
  const float* nas    = (const float*)d_in[13];
  const float* wout   = (const float*)d_in[14];
  const float* bout   = (const float*)d_in[15];
  const float* n2s    = (const float*)d_in[16];
  const float* wgate  = (const float*)d_in[17];
  const float* wval   = (const float*)d_in[18];
  const float* wffn   = (const float*)d_in[19];

  float* out_hs  = (float*)d_out;            // [2,8,64,64]
  float* out_ffn = (float*)d_out + 65536;    // [2,1024,512]

  char* p = (char*)d_ws;
  auto alloc = [&](size_t bytes) -> char* {
    char* r = p; p += (bytes + 255) & ~(size_t)255; return r;
  };
  bf16*  wqkvT = (bf16*)alloc((size_t)1536 * 512 * 2);
  bf16*  wbuvT = (bf16*)alloc((size_t)1024 * 512 * 2);
  bf16*  woutT = (bf16*)alloc((size_t)512 * 512 * 2);
  bf16*  wgvT  = (bf16*)alloc((size_t)4096 * 512 * 2);   // gate/val row-interleaved (128-groups)
  bf16*  wffnT = (bf16*)alloc((size_t)512 * 2048 * 2);
  float* qkvF  = (float*)alloc((size_t)M_ * 1536 * 4);
  float* buvF  = (float*)alloc((size_t)M_ * 1024 * 4);
  float* betaF = (float*)alloc((size_t)M_ * 8 * 4);
  float* alphaF= (float*)alloc((size_t)M_ * 8 * 4);
  float* scal8 = (float*)alloc((size_t)M_ * 8 * 8 * 4);
  float* attnF = (float*)alloc((size_t)M_ * 512 * 4);
  bf16*  attnB = (bf16*)alloc((size_t)M_ * 512 * 2);
  float* skipF = (float*)alloc((size_t)M_ * 512 * 4);
  bf16*  h2B   = (bf16*)alloc((size_t)M_ * 512 * 2);
  bf16*  ffnB  = (bf16*)alloc((size_t)M_ * 2048 * 2);
  char*  tail  = alloc((size_t)32 * 1024 * 1024);
  if ((size_t)(p - (char*)d_ws) > ws_size) return;  // workspace too small

  float* hF  = (float*)tail;                               // 4 MiB
  bf16*  hB  = (bf16*)(tail + ((size_t)4 << 20));          // 2 MiB
  float* aeF = (float*)(tail + ((size_t)6 << 20));         // 4 MiB
  bf16*  aeB = (bf16*)(tail + ((size_t)10 << 20));         // 2 MiB

  bf16*  PtHi = (bf16*)tail;                               // 4 MiB
  bf16*  PtLo = (bf16*)(tail + ((size_t)4 << 20));         // 4 MiB
  float* UtB  = (float*)(tail + ((size_t)8 << 20));        // 8 MiB
  float* Hbuf = (float*)(tail + ((size_t)16 << 20));       // 8 MiB
  float* Qtb  = (float*)(tail + ((size_t)24 << 20));       // 4 MiB
  float* Vtb  = (float*)(tail + ((size_t)28 << 20));       // 4 MiB

  TTab tab;
  tab.j[0] = {wq,    wqkvT,              512,  512,  0,    0};
  tab.j[1] = {wk,    wqkvT + 512 * 512,  512,  512,  256,  0};
  tab.j[2] = {wv,    wqkvT + 1024 * 512, 512,  512,  512,  0};
  tab.j[3] = {wbu,   wbuvT,              512,  512,  768,  0};
  tab.j[4] = {wbv,   wbuvT + 512 * 512,  512,  512,  1024, 0};
  tab.j[5] = {wout,  woutT,              512,  512,  1280, 0};
  tab.j[6] = {wgate, wgvT,               512,  2048, 1536, 1};
  tab.j[7] = {wval,  wgvT,               512,  2048, 2560, 2};
  tab.j[8] = {wffn,  wffnT,              2048, 512,  3584, 0};
  k_transpose_all<<<4608, dim3(32, 8), 0, stream>>>(tab);

  k_pre<<<M_ * 2, 256, 0, stream>>>(x, n1s, hF, hB, action, embed, aeF, aeB);

  k_gemm3<1><<<dim3(1536 / 128, M_ / 128), 512, 0, stream>>>(hB, wqkvT, qkvF, M_, 1536, 512, 1024);
  k_gemm2<0><<<dim3(1024 / 64, M_ / 64), 256, 0, stream>>>(aeB, wbuvT, buvF, M_, 1024, 512, 0, nullptr, nullptr);
  k_dot8x2<<<M_, 256, 0, stream>>>(hF, aeF, wbeta, walpha, betaF, alphaF);
  k_qknorm_dots<<<M_ * 2, 256, 0, stream>>>(qkvF, buvF, betaF, alphaF, mask, scal8);
  // hF/hB/aeF/aeB dead from here; tail region is reused by the chunk buffers.

  k_scan_chunk<<<16 * CHUNKS_, 512, 0, stream>>>(qkvF, buvF, scal8, PtHi, PtLo, UtB, Qtb, Vtb);
  k_chain3<<<64, 64, 0, stream>>>(PtHi, PtLo, UtB, carry, Hbuf, out_hs);
  k_attn_gemm<<<16 * CHUNKS_, 256, 0, stream>>>(Hbuf, Qtb, Vtb, attnF);

  k_rmsnorm<<<M_, 256, 0, stream>>>(attnF, nas, nullptr, attnB);
  k_gemm2<2><<<dim3(512 / 64, M_ / 64), 256, 0, stream>>>(attnB, woutT, skipF, M_, 512, 512, 0, bout, x);
  k_rmsnorm<<<M_, 256, 0, stream>>>(skipF, n2s, nullptr, h2B);
  k_gemm3<4><<<dim3(4096 / 128, M_ / 128), 512, 0, stream>>>(h2B, wgvT, ffnB, M_, 4096, 512, 0);
  k_gemm2<3><<<dim3(512 / 64, M_ / 64), 256, 0, stream>>>(ffnB, wffnT, out_ffn, M_, 512, 2048, 0, nullptr, skipF);
}